// Round 6
// baseline (181.540 us; speedup 1.0000x reference)
//
#include <hip/hip_runtime.h>

// Attention_msa_TwoStream. Only v_cls (d_in[1]) feeds outputs (MLP/q/k dead).
// N=3200, H=8, d=64, C=512; fp32 I/O; bf16 MFMA internals.
// Pipeline (3 dispatches, no memset, no atomics, no K-loop barriers):
//   k_prep  : per-(n,h) L2 norm; vnfull bf16 + vT/vnT transposes + x_ori.
//   k_rgemm : bid 0-15   -> G_h partials (h x K-half), direct-global NT GEMM.
//             bid 16-1290-> R = 1/8 vn.vn^T upper-tri 64x64 tiles (1275 blocks
//                          -> ~5 waves/SIMD of TLP; r5's 128x128/341-block grid
//                          was latency-bound at 1.3 waves/SIMD). vnfull is
//                          3.3 MB (L2-resident): direct global frag reads,
//                          register ping-pong, zero barriers in the K-loop.
//                          Epilogue stages tile (+transpose for off-diag) in
//                          padded LDS -> full-line 16B row writes.
//   k_fused : rows: Z/E row-sum + normalize -> out2 | tiles: X = vn.(G0+G1) - corr.

#define NN 3200
#define HEADS 8
#define DH 64
#define CC 512

typedef __attribute__((ext_vector_type(8))) short short8;   // 8 bf16
typedef __attribute__((ext_vector_type(4))) float f32x4;

static __device__ __forceinline__ unsigned short f2b(float f) {
  union { float f; unsigned u; } x; x.f = f;
  unsigned r = x.u + 0x7FFFu + ((x.u >> 16) & 1u);   // RTN-even
  return (unsigned short)(r >> 16);
}
static __device__ __forceinline__ float b2f(unsigned short s) {
  union { unsigned u; float f; } x; x.u = ((unsigned)s) << 16; return x.f;
}
static __device__ __forceinline__ short8 pack8(f32x4 lo, f32x4 hi) {
  short8 r;
  r[0] = (short)f2b(lo[0]); r[1] = (short)f2b(lo[1]);
  r[2] = (short)f2b(lo[2]); r[3] = (short)f2b(lo[3]);
  r[4] = (short)f2b(hi[0]); r[5] = (short)f2b(hi[1]);
  r[6] = (short)f2b(hi[2]); r[7] = (short)f2b(hi[3]);
  return r;
}

// ---------------------------------------------------------------------------
// k_prep: per-(n,h) L2 norm; vnfull bf16 (cached - heavy reuse), vT/vnT bf16
// transposes + x_ori f32 (non-temporal - streaming). No atomics, no MFMA.
__global__ __launch_bounds__(256) void k_prep(const float* __restrict__ v,
                                              unsigned short* __restrict__ vnfull,
                                              unsigned short* __restrict__ vT,
                                              unsigned short* __restrict__ vnT,
                                              float* __restrict__ out) {
  __shared__ unsigned short tileV[DH][72];   // [dim][row]
  __shared__ unsigned short tileN[DH][72];
  int h  = blockIdx.x & 7;
  int n0 = (int)(blockIdx.x >> 3) * 64;
  int j  = threadIdx.x & 63;       // dim within head
  int w  = threadIdx.x >> 6;       // wave = row group
  #pragma unroll
  for (int i = 0; i < 16; i++) {
    int n = n0 + w * 16 + i;
    float val = v[(size_t)n * CC + h * DH + j];
    float ss = val * val;
    #pragma unroll
    for (int off = 32; off >= 1; off >>= 1) ss += __shfl_xor(ss, off, 64);
    float inv = 1.0f / (sqrtf(ss) + 1e-8f);
    unsigned short un = f2b(val * inv);
    tileV[j][w * 16 + i] = f2b(val);
    tileN[j][w * 16 + i] = un;
    vnfull[(size_t)n * CC + h * DH + j] = un;
    __builtin_nontemporal_store(val, out + (size_t)n * (2 * CC) + CC + h * DH + j);
  }
  __syncthreads();
  #pragma unroll
  for (int i = 0; i < 16; i++) {
    int jj = w * 16 + i;
    __builtin_nontemporal_store(tileV[jj][j], vT  + ((size_t)h * DH + jj) * NN + n0 + j);
    __builtin_nontemporal_store(tileN[jj][j], vnT + ((size_t)h * DH + jj) * NN + n0 + j);
  }
}

// ---------------------------------------------------------------------------
// k_rgemm: bid 0-15: G_h partials. bid 16-1290: upper-tri 64x64 R tiles,
// LDS-free K-loop (direct global reads from L2-resident vnfull).
__global__ __launch_bounds__(256) void k_rgemm(const unsigned short* __restrict__ vnfull,
                                               const unsigned short* __restrict__ vT,
                                               const unsigned short* __restrict__ vnT,
                                               float* __restrict__ Gf,
                                               unsigned short* __restrict__ Rg) {
  __shared__ __align__(16) unsigned short S[64][68];    // 8.7 KB (pad 68: no conflicts)
  __shared__ __align__(16) unsigned short S2[64][68];   // transposed copy (off-diag)
  int bid = (int)blockIdx.x;
  int tid = threadIdx.x;
  int lane = tid & 63, quad = lane >> 4, l16 = lane & 15;

  if (bid < 16) {
    // ---- G partial: G[half][h][d][k] = sum_{m in half} V[m][d]*vn[m][k] --
    int h = bid >> 1, half = bid & 1, w = tid >> 6;
    int mbase = half * 1600;
    const unsigned short* aP = vT + (size_t)(h * DH + w * 16 + l16) * NN + quad * 8 + mbase;
    const unsigned short* bP[4];
    #pragma unroll
    for (int ct = 0; ct < 4; ct++)
      bP[ct] = vnT + (size_t)(h * DH + ct * 16 + l16) * NN + quad * 8 + mbase;
    f32x4 acc4[4];
    #pragma unroll
    for (int ct = 0; ct < 4; ct++) acc4[ct] = (f32x4){0.f, 0.f, 0.f, 0.f};
    #pragma unroll 2
    for (int m0 = 0; m0 < 1600; m0 += 64) {
      short8 a0 = *(const short8*)(aP + m0);
      short8 a1 = *(const short8*)(aP + m0 + 32);
      #pragma unroll
      for (int ct = 0; ct < 4; ct++) {
        short8 b0 = *(const short8*)(bP[ct] + m0);
        short8 b1 = *(const short8*)(bP[ct] + m0 + 32);
        acc4[ct] = __builtin_amdgcn_mfma_f32_16x16x32_bf16(a0, b0, acc4[ct], 0, 0, 0);
        acc4[ct] = __builtin_amdgcn_mfma_f32_16x16x32_bf16(a1, b1, acc4[ct], 0, 0, 0);
      }
    }
    #pragma unroll
    for (int ct = 0; ct < 4; ct++)
      #pragma unroll
      for (int g = 0; g < 4; g++)
        Gf[(size_t)half * 32768 + h * 4096 +
           (w * 16 + quad * 4 + g) * 64 + ct * 16 + l16] = acc4[ct][g];
    return;
  }
  bid -= 16;

  // upper-triangular (incl. diagonal) 64-tile map: bid -> (bi, bj), bj >= bi
  int bi = 0;
  while (bid >= 50 - bi) { bid -= 50 - bi; bi++; }
  int bj = bi + bid;
  int n0 = bi * 64, m0 = bj * 64;
  int w = tid >> 6;   // wave: rows w*16 .. w*16+15

  // per-wave direct-global fragment pointers (A: own 16 rows; B: all 64 cols)
  const unsigned short* pA = vnfull + (size_t)(n0 + w * 16 + l16) * CC + quad * 8;
  const unsigned short* pB = vnfull + (size_t)(m0 + l16) * CC + quad * 8;

  f32x4 acc4[4];
  #pragma unroll
  for (int ct = 0; ct < 4; ct++) acc4[ct] = (f32x4){0.f, 0.f, 0.f, 0.f};

#define LOADK(A_, B_, KK)                                                     \
  do {                                                                        \
    A_ = *(const short8*)(pA + (KK) * 32);                                    \
    _Pragma("unroll")                                                         \
    for (int ct = 0; ct < 4; ct++)                                            \
      B_[ct] = *(const short8*)(pB + ct * 16 * CC + (KK) * 32);               \
  } while (0)

#define MFMAK(A_, B_)                                                         \
  do {                                                                        \
    _Pragma("unroll")                                                         \
    for (int ct = 0; ct < 4; ct++)                                            \
      acc4[ct] = __builtin_amdgcn_mfma_f32_16x16x32_bf16(A_, B_[ct],          \
                                                         acc4[ct], 0, 0, 0);  \
  } while (0)

  // register ping-pong: loads for step k+1 in flight under step k's MFMAs
  short8 aPi, bPi[4], aQi, bQi[4];
  LOADK(aPi, bPi, 0);
  #pragma unroll
  for (int kp = 0; kp < 7; kp++) {
    LOADK(aQi, bQi, 2 * kp + 1);
    MFMAK(aPi, bPi);
    LOADK(aPi, bPi, 2 * kp + 2);
    MFMAK(aQi, bQi);
  }
  LOADK(aQi, bQi, 15);
  MFMAK(aPi, bPi);
  MFMAK(aQi, bQi);
#undef LOADK
#undef MFMAK

  // ---- epilogue: transform -> padded-LDS stage (both orientations) -------
  bool offdiag = (bi != bj);
  #pragma unroll
  for (int g = 0; g < 4; g++) {
    int r = w * 16 + quad * 4 + g;
    int n = n0 + r;
    int bs = (n / 10) * 10;
    #pragma unroll
    for (int ct = 0; ct < 4; ct++) {
      int c = ct * 16 + l16;
      int m = m0 + c;
      float R = acc4[ct][g] * 0.125f;
      float eR = __expf(R);
      bool sel = (R > 0.75f);
      bool zz = (m >= bs) & (m < bs + 9) & (m != n);
      float ef = zz ? 1.0f : eR;              // exp(0)=1
      S[r][c] = f2b(sel ? ef : -ef);
      if (offdiag) {
        int bsm = (m / 10) * 10;
        bool zz2 = (n >= bsm) & (n < bsm + 9) & (m != n);
        float ef2 = zz2 ? 1.0f : eR;
        S2[c][r] = f2b(sel ? ef2 : -ef2);
      }
    }
  }
  __syncthreads();

  // ---- coalesced row writes: 4 threads x 2 chunks of 16B per row ---------
  {
    int r2 = tid >> 2;
    #pragma unroll
    for (int i = 0; i < 2; i++) {
      int s = (tid & 3) * 2 + i;
      *(short8*)(Rg + (size_t)(n0 + r2) * NN + m0 + s * 8) =
          *(const short8*)&S[r2][s * 8];
      if (offdiag)
        *(short8*)(Rg + (size_t)(m0 + r2) * NN + n0 + s * 8) =
            *(const short8*)&S2[r2][s * 8];
    }
  }
}

// ---------------------------------------------------------------------------
// k_fused: blocks [0,800): out2 rows (wave-per-row Z/E sum + normalize);
//          blocks [800,1200): k_x tiles (X = vn.(G0+G1) - zone corr).
__global__ __launch_bounds__(256) void k_fused(const unsigned short* __restrict__ Rg,
                                               const unsigned short* __restrict__ vnfull,
                                               const float* __restrict__ Gf,
                                               const unsigned short* __restrict__ vT,
                                               float* __restrict__ out2,
                                               float* __restrict__ out) {
  int bid = (int)blockIdx.x;
  if (bid < 800) {
    // ---- softmax rows: n = bid*4 + wave ---------------------------------
    int w = threadIdx.x >> 6, lane = threadIdx.x & 63;
    int n = bid * 4 + w;
    const unsigned short* rp = Rg + (size_t)n * NN;
    short8 s[7];
    float z = 0.f, e = 0.f;
    #pragma unroll
    for (int i = 0; i < 7; i++) {
      int c = lane + i * 64;              // chunk of 8 bf16; 400 chunks/row
      if (c < 400) {
        s[i] = *(const short8*)(rp + c * 8);   // temporal: L3 hit after k_rgemm
        #pragma unroll
        for (int j = 0; j < 8; j++) {
          float val = b2f((unsigned short)s[i][j]);
          z += fabsf(val);
          e += fmaxf(val, 0.f);
        }
      }
    }
    #pragma unroll
    for (int off = 1; off <= 32; off <<= 1) {
      z += __shfl_xor(z, off, 64);
      e += __shfl_xor(e, off, 64);
    }
    float rd = 1.0f / (e + 1e-8f * z);
    float* op = out2 + (size_t)n * NN;
    #pragma unroll
    for (int i = 0; i < 7; i++) {
      int c = lane + i * 64;
      if (c < 400) {
        f32x4 o0, o1;
        #pragma unroll
        for (int j = 0; j < 4; j++) {
          float a = b2f((unsigned short)s[i][j]);
          o0[j] = (a > 0.f) ? a * rd : 0.f;
          float b = b2f((unsigned short)s[i][4 + j]);
          o1[j] = (b > 0.f) ? b * rd : 0.f;
        }
        __builtin_nontemporal_store(o0, (f32x4*)(op + c * 8));
        __builtin_nontemporal_store(o1, (f32x4*)(op + c * 8 + 4));
      }
    }
  } else {
    // ---- X tiles: X_h[n][d] = vn.G - zone correction --------------------
    bid -= 800;
    __shared__ __align__(16) unsigned short Sz[4][16][48];
    int hl   = threadIdx.x >> 6;
    int h    = (bid & 1) * 4 + hl;
    int lane = threadIdx.x & 63;
    int quad = lane >> 4, l16 = lane & 15;
    int n0 = (bid >> 1) * 16;
    int lo = (n0 / 10) * 10;                    // zone window [lo, lo+32)

    short8 aZ[2];
    #pragma unroll
    for (int kh = 0; kh < 2; kh++)
      aZ[kh] = *(const short8*)(vnfull + (size_t)(n0 + l16) * CC + h * DH + kh * 32 + quad * 8);

    #pragma unroll
    for (int ct = 0; ct < 2; ct++) {
      int rB = lo + ct * 16 + l16;
      int rC = rB < NN ? rB : NN - 1;           // clamp OOB (mask kills it)
      short8 b0 = *(const short8*)(vnfull + (size_t)rC * CC + h * DH + quad * 8);
      short8 b1 = *(const short8*)(vnfull + (size_t)rC * CC + h * DH + 32 + quad * 8);
      f32x4 cS = (f32x4){0.f, 0.f, 0.f, 0.f};
      cS = __builtin_amdgcn_mfma_f32_16x16x32_bf16(aZ[0], b0, cS, 0, 0, 0);
      cS = __builtin_amdgcn_mfma_f32_16x16x32_bf16(aZ[1], b1, cS, 0, 0, 0);
      int m = lo + ct * 16 + l16;
      #pragma unroll
      for (int g = 0; g < 4; g++) {
        int n = n0 + quad * 4 + g;
        int bs = (n / 10) * 10;
        bool keep = (m >= bs) & (m < bs + 9) & (m != n);
        Sz[hl][quad * 4 + g][ct * 16 + l16] = f2b(keep ? -cS[g] : 0.f);
      }
    }
    __syncthreads();

    f32x4 xr[4];
    #pragma unroll
    for (int nt = 0; nt < 4; nt++) {
      const float* gp = Gf + (size_t)h * 4096 + (nt * 16 + l16) * 64 + quad * 8;
      f32x4 lo0 = *(const f32x4*)gp        + *(const f32x4*)(gp + 32768);
      f32x4 hi0 = *(const f32x4*)(gp + 4)  + *(const f32x4*)(gp + 4 + 32768);
      f32x4 lo1 = *(const f32x4*)(gp + 32) + *(const f32x4*)(gp + 32 + 32768);
      f32x4 hi1 = *(const f32x4*)(gp + 36) + *(const f32x4*)(gp + 36 + 32768);
      short8 g0 = pack8(lo0, hi0);
      short8 g1 = pack8(lo1, hi1);
      f32x4 cX = (f32x4){0.f, 0.f, 0.f, 0.f};
      cX = __builtin_amdgcn_mfma_f32_16x16x32_bf16(aZ[0], g0, cX, 0, 0, 0);
      cX = __builtin_amdgcn_mfma_f32_16x16x32_bf16(aZ[1], g1, cX, 0, 0, 0);
      xr[nt] = cX;
    }

    short8 aC = *(const short8*)&Sz[hl][l16][quad * 8];
    #pragma unroll
    for (int nt = 0; nt < 4; nt++) {
      short8 b = *(const short8*)(vT + (size_t)(h * DH + nt * 16 + l16) * NN + lo + quad * 8);
      xr[nt] = __builtin_amdgcn_mfma_f32_16x16x32_bf16(aC, b, xr[nt], 0, 0, 0);
    }

    #pragma unroll
    for (int nt = 0; nt < 4; nt++)
      #pragma unroll
      for (int g = 0; g < 4; g++)
        __builtin_nontemporal_store(xr[nt][g],
            out + (size_t)(n0 + quad * 4 + g) * (2 * CC) + h * DH + nt * 16 + l16);
  }
}

// ---------------------------------------------------------------------------
extern "C" void kernel_launch(void* const* d_in, const int* in_sizes, int n_in,
                              void* d_out, int out_size, void* d_ws, size_t ws_size,
                              hipStream_t stream) {
  const float* v = (const float*)d_in[1];   // only live input
  float* out = (float*)d_out;

  // ws carve (~31 MB): [Gf 2x32768] f32, [vnfull][vT][vnT] bf16, [Rg] bf16
  float* Gf = (float*)d_ws;
  unsigned short* vnfull = (unsigned short*)(Gf + 2 * HEADS * DH * DH);
  unsigned short* vT  = vnfull + (size_t)NN * CC;
  unsigned short* vnT = vT + (size_t)NN * CC;
  unsigned short* Rg  = vnT + (size_t)NN * CC;

  k_prep<<<dim3(HEADS * (NN / 64)), dim3(256), 0, stream>>>(v, vnfull, vT, vnT, out);
  k_rgemm<<<dim3(16 + 1275), dim3(256), 0, stream>>>(vnfull, vT, vnT, Gf, Rg);
  k_fused<<<dim3(800 + (NN / 16) * 2), dim3(256), 0, stream>>>(
      Rg, vnfull, Gf, vT, out + (size_t)NN * 2 * CC, out);
}